// Round 8
// baseline (10.932 us; speedup 1.0000x reference)
//
#include <hip/hip_runtime.h>
#include <math.h>

#define DIM 4096
#define BATCH 8192
#define NT 1024
#define NWAVES (NT / 64)
#define RPT (BATCH / NT)   // betas per thread = 8

// DPP-based wave64 inclusive scan step: x += dpp_shifted(x), on the VALU pipe.
template <int CTRL, int ROWMASK>
__device__ __forceinline__ float dpp_add(float x) {
    int t = __builtin_amdgcn_update_dpp(0, __float_as_int(x),
                                        CTRL, ROWMASK, 0xf, true);
    return x + __int_as_float(t);
}

// Kogge-Stone inclusive scan across 64 lanes (lane 63 = wave total).
__device__ __forceinline__ float wave_scan(float x) {
    x = dpp_add<0x111, 0xf>(x);   // row_shr:1
    x = dpp_add<0x112, 0xf>(x);   // row_shr:2
    x = dpp_add<0x114, 0xf>(x);   // row_shr:4
    x = dpp_add<0x118, 0xf>(x);   // row_shr:8
    x = dpp_add<0x142, 0xa>(x);   // row_bcast:15 -> rows 1,3
    x = dpp_add<0x143, 0xc>(x);   // row_bcast:31 -> rows 2,3
    return x;
}

// round-to-nearest bf16 (kept in the HIGH 16 bits of the u32)
__device__ __forceinline__ unsigned int bf16_hi(float x) {
    return (__float_as_uint(x) + 0x8000u) & 0xffff0000u;
}

// Single-block fused kernel. Round-7 structure with the prefix table packed
// as 4 x bf16 per bin (uint2, 8 B) -> phase-2 gathers are ds_read_b64 with
// half the bank traffic of b128. Scan itself stays full f32; only the stored
// table is quantized (error ~1e-3 relative on lhs, threshold is 2%).
__global__ __launch_bounds__(NT)
void calc_kernel(const float* __restrict__ betas,
                 const float* __restrict__ lambdas,
                 const float* __restrict__ gammas,
                 float* __restrict__ out)
{
    __shared__ uint2  s2[DIM];        // 32 KB packed prefix table
    __shared__ float4 ovl4[NWAVES];   // per-wave totals of the 4 series
    __shared__ float4 red4[NWAVES];   // per-wave phase-2 partial sums

    const int t = threadIdx.x;
    const int lane = t & 63;
    const int wave = t >> 6;
    const int j0 = t * 4;

    // ---- all global loads up front (cold-HBM latency hides under math) ----
    const float4 la4 = *reinterpret_cast<const float4*>(lambdas + j0);
    const float4 ga4 = *reinterpret_cast<const float4*>(gammas + j0);
    const float4* b4p = reinterpret_cast<const float4*>(betas);
    const float4 bv0 = b4p[t];
    const float4 bv1 = b4p[NT + t];

    // ---- K + logK per beta, divide-free ----
    // reference kf = f32roundtrip(beta)-1 = beta-1 within ~3 ulp; floor can
    // differ only for betas ~1e-3 from an integer (few per 8192, each worth
    // ~0.25 on ixt vs ~400 budget).
    float bet[RPT] = { bv0.x, bv0.y, bv0.z, bv0.w, bv1.x, bv1.y, bv1.z, bv1.w };
    int   K[RPT];
    float lk[RPT];
    #pragma unroll
    for (int r = 0; r < RPT; ++r) {
        int k = (int)floorf(bet[r] - 1.0f);
        k = min(max(k, 1), DIM - 1);
        K[r]  = k;
        lk[r] = __logf((float)k);
    }

    // ---- per-element series values ----
    float las[4] = { la4.x, la4.y, la4.z, la4.w };
    float gas[4] = { ga4.x, ga4.y, ga4.z, ga4.w };
    float e[4][4];
    float tot0 = 0.f, tot1 = 0.f, tot2 = 0.f, tot3 = 0.f;
    #pragma unroll
    for (int i = 0; i < 4; ++i) {
        float g = gas[i];
        float l = las[i];
        float v0 = g;
        float v1 = g * __logf((float)(j0 + i + 1));
        float v2 = g * __logf(l);
        float v3 = g * __logf(1.0f - l);     // lam in (0.05,0.95): safe as log
        e[i][0] = v0; e[i][1] = v1; e[i][2] = v2; e[i][3] = v3;
        tot0 += v0; tot1 += v1; tot2 += v2; tot3 += v3;
    }

    // ---- wave-level inclusive scan of per-thread totals (DPP, VALU pipe) ----
    float i0 = wave_scan(tot0);
    float i1 = wave_scan(tot1);
    float i2 = wave_scan(tot2);
    float i3 = wave_scan(tot3);
    if (lane == 63) ovl4[wave] = make_float4(i0, i1, i2, i3);
    __syncthreads();

    // cross-wave base: sum preceding wave totals (broadcast b128 reads)
    float b0 = i0 - tot0, b1 = i1 - tot1, b2 = i2 - tot2, b3 = i3 - tot3;
    for (int w = 0; w < wave; ++w) {
        float4 o = ovl4[w];
        b0 += o.x; b1 += o.y; b2 += o.z; b3 += o.w;
    }
    #pragma unroll
    for (int i = 0; i < 4; ++i) {
        b0 += e[i][0]; b1 += e[i][1]; b2 += e[i][2]; b3 += e[i][3];
        // pack {b0,b1} and {b2,b3} as bf16 pairs (RN): hi16 | lo16
        unsigned int w0 = bf16_hi(b0) | (bf16_hi(b1) >> 16);
        unsigned int w1 = bf16_hi(b2) | (bf16_hi(b3) >> 16);
        s2[j0 + i] = make_uint2(w0, w1);
    }
    __syncthreads();

    // ---- per-beta gathers (b64, half the bank traffic of b128) ----
    float a0 = 0.f, a1 = 0.f, a2 = 0.f, a3 = 0.f;
    #pragma unroll
    for (int r = 0; r < RPT; ++r) {
        uint2 w = s2[K[r] - 1];            // inclusive prefix at K-1 == sum_{j<K}
        float G  = __uint_as_float(w.x & 0xffff0000u);
        float P1 = __uint_as_float(w.x << 16);
        float P2 = __uint_as_float(w.y & 0xffff0000u);
        float P3 = __uint_as_float(w.y << 16);
        a0 += lk[r] * G - P1;              // ixt contribution
        a1 += G;                           // n_I
        a2 += P2;                          // S_lambda
        a3 += P3;                          // S_lambda_comp
    }

    // ---- per-wave reduce via DPP scan (lane 63 holds total) ----
    a0 = wave_scan(a0);
    a1 = wave_scan(a1);
    a2 = wave_scan(a2);
    a3 = wave_scan(a3);
    if (lane == 63) red4[wave] = make_float4(a0, a1, a2, a3);
    __syncthreads();

    if (t == 0) {
        float s0 = 0.f, s1 = 0.f, s2r = 0.f, s3 = 0.f;
        #pragma unroll
        for (int w = 0; w < NWAVES; ++w) {
            float4 rv = red4[w];
            s0 += rv.x; s1 += rv.y; s2r += rv.z; s3 += rv.w;
        }
        float ixt = s0;
        float nI  = s1;
        float inv_nI = 1.0f / nI;
        float gm_term  = __expf(s2r * inv_nI);
        float gm_comp  = __expf(s3  * inv_nI);
        float exp_term = __expf(2.0f * ixt * inv_nI);
        float log_term = -nI * 0.5f * __logf(gm_comp + exp_term * gm_term);
        float rhs = 1.0f - (ixt + log_term);   // IXY = 1
        float l1  = 1.0f - ixt * 0.1f;         // HX = 10
        if (l1 < 0.0f) l1 = fabsf(l1) * 20.0f;
        out[0] = rhs;
        out[1] = l1 * l1;                      // C=1, ALPHA=2
    }
}

extern "C" void kernel_launch(void* const* d_in, const int* in_sizes, int n_in,
                              void* d_out, int out_size, void* d_ws, size_t ws_size,
                              hipStream_t stream) {
    const float* betas   = (const float*)d_in[0];
    const float* lambdas = (const float*)d_in[1];
    const float* gammas  = (const float*)d_in[2];
    calc_kernel<<<1, NT, 0, stream>>>(betas, lambdas, gammas, (float*)d_out);
}

// Round 9
// 10.578 us; speedup vs baseline: 1.0335x; 1.0335x over previous
//
#include <hip/hip_runtime.h>
#include <math.h>

#define DIM 4096
#define BATCH 8192
#define NT 1024
#define NWAVES (NT / 64)
#define RPT (BATCH / NT)   // betas per thread = 8

// DPP-based wave64 inclusive scan step: x += dpp_shifted(x), on the VALU pipe
// (no ds_bpermute). CDNA keeps GCN row_shr / row_bcast15 / row_bcast31.
template <int CTRL, int ROWMASK>
__device__ __forceinline__ float dpp_add(float x) {
    int t = __builtin_amdgcn_update_dpp(0, __float_as_int(x),
                                        CTRL, ROWMASK, 0xf, true);
    return x + __int_as_float(t);
}

// Kogge-Stone inclusive scan across 64 lanes: row_shr 1,2,4,8 within 16-lane
// rows, then row_bcast15 (rows 1,3) and row_bcast31 (rows 2,3).
__device__ __forceinline__ float wave_scan(float x) {
    x = dpp_add<0x111, 0xf>(x);   // row_shr:1
    x = dpp_add<0x112, 0xf>(x);   // row_shr:2
    x = dpp_add<0x114, 0xf>(x);   // row_shr:4
    x = dpp_add<0x118, 0xf>(x);   // row_shr:8
    x = dpp_add<0x142, 0xa>(x);   // row_bcast:15 -> rows 1,3
    x = dpp_add<0x143, 0xc>(x);   // row_bcast:31 -> rows 2,3
    return x;                     // lane 63 = wave total
}

// Single-block fused kernel (round-7 best: f32 table, DPP scans, divide-free K).
// Measured floor analysis: ~5us fixed dispatch/replay overhead + ~5.5us
// latency-dominated single-CU work (cold-HBM 96KB pull, 2 barriers, ramp).
// r8 falsified the LDS-gather-bound hypothesis (bf16 table regressed).
__global__ __launch_bounds__(NT)
void calc_kernel(const float* __restrict__ betas,
                 const float* __restrict__ lambdas,
                 const float* __restrict__ gammas,
                 float* __restrict__ out)
{
    __shared__ float4 s4[DIM];        // 64 KB prefix table
    __shared__ float4 ovl4[NWAVES];   // per-wave totals of the 4 series
    __shared__ float4 red4[NWAVES];   // per-wave phase-2 partial sums

    const int t = threadIdx.x;
    const int lane = t & 63;
    const int wave = t >> 6;
    const int j0 = t * 4;

    // ---- all global loads up front (hide cold-HBM latency under math) ----
    const float4 la4 = *reinterpret_cast<const float4*>(lambdas + j0);
    const float4 ga4 = *reinterpret_cast<const float4*>(gammas + j0);
    const float4* b4p = reinterpret_cast<const float4*>(betas);
    const float4 bv0 = b4p[t];
    const float4 bv1 = b4p[NT + t];

    // ---- K + logK per beta, divide-free ----
    // reference kf = f32roundtrip(beta)-1 = beta-1 within ~3 ulp; floor can
    // differ only for betas ~1e-3 from an integer (few per 8192, each worth
    // ~0.25 on ixt vs ~400 budget).
    float bet[RPT] = { bv0.x, bv0.y, bv0.z, bv0.w, bv1.x, bv1.y, bv1.z, bv1.w };
    int   K[RPT];
    float lk[RPT];
    #pragma unroll
    for (int r = 0; r < RPT; ++r) {
        int k = (int)floorf(bet[r] - 1.0f);
        k = min(max(k, 1), DIM - 1);
        K[r]  = k;
        lk[r] = __logf((float)k);
    }

    // ---- per-element series values ----
    float las[4] = { la4.x, la4.y, la4.z, la4.w };
    float gas[4] = { ga4.x, ga4.y, ga4.z, ga4.w };
    float e[4][4];
    float tot0 = 0.f, tot1 = 0.f, tot2 = 0.f, tot3 = 0.f;
    #pragma unroll
    for (int i = 0; i < 4; ++i) {
        float g = gas[i];
        float l = las[i];
        float v0 = g;
        float v1 = g * __logf((float)(j0 + i + 1));
        float v2 = g * __logf(l);
        float v3 = g * __logf(1.0f - l);     // lam in (0.05,0.95): safe as log
        e[i][0] = v0; e[i][1] = v1; e[i][2] = v2; e[i][3] = v3;
        tot0 += v0; tot1 += v1; tot2 += v2; tot3 += v3;
    }

    // ---- wave-level inclusive scan of per-thread totals (DPP, VALU pipe) ----
    float i0 = wave_scan(tot0);
    float i1 = wave_scan(tot1);
    float i2 = wave_scan(tot2);
    float i3 = wave_scan(tot3);
    if (lane == 63) ovl4[wave] = make_float4(i0, i1, i2, i3);
    __syncthreads();

    // cross-wave base: sum preceding wave totals (broadcast b128 reads)
    float b0 = i0 - tot0, b1 = i1 - tot1, b2 = i2 - tot2, b3 = i3 - tot3;
    for (int w = 0; w < wave; ++w) {
        float4 o = ovl4[w];
        b0 += o.x; b1 += o.y; b2 += o.z; b3 += o.w;
    }
    #pragma unroll
    for (int i = 0; i < 4; ++i) {
        b0 += e[i][0]; b1 += e[i][1]; b2 += e[i][2]; b3 += e[i][3];
        s4[j0 + i] = make_float4(b0, b1, b2, b3);
    }
    __syncthreads();

    // ---- per-beta gathers ----
    float a0 = 0.f, a1 = 0.f, a2 = 0.f, a3 = 0.f;
    #pragma unroll
    for (int r = 0; r < RPT; ++r) {
        float4 p = s4[K[r] - 1];       // inclusive prefix at K-1 == sum_{j<K}
        a0 += lk[r] * p.x - p.y;       // ixt contribution
        a1 += p.x;                     // n_I
        a2 += p.z;                     // S_lambda
        a3 += p.w;                     // S_lambda_comp
    }

    // ---- per-wave reduce via DPP scan (lane 63 holds total) ----
    a0 = wave_scan(a0);
    a1 = wave_scan(a1);
    a2 = wave_scan(a2);
    a3 = wave_scan(a3);
    if (lane == 63) red4[wave] = make_float4(a0, a1, a2, a3);
    __syncthreads();

    if (t == 0) {
        float s0 = 0.f, s1 = 0.f, s2 = 0.f, s3 = 0.f;
        #pragma unroll
        for (int w = 0; w < NWAVES; ++w) {
            float4 rv = red4[w];
            s0 += rv.x; s1 += rv.y; s2 += rv.z; s3 += rv.w;
        }
        float ixt = s0;
        float nI  = s1;
        float inv_nI = 1.0f / nI;
        float gm_term  = __expf(s2 * inv_nI);
        float gm_comp  = __expf(s3 * inv_nI);
        float exp_term = __expf(2.0f * ixt * inv_nI);
        float log_term = -nI * 0.5f * __logf(gm_comp + exp_term * gm_term);
        float rhs = 1.0f - (ixt + log_term);   // IXY = 1
        float l1  = 1.0f - ixt * 0.1f;         // HX = 10
        if (l1 < 0.0f) l1 = fabsf(l1) * 20.0f;
        out[0] = rhs;
        out[1] = l1 * l1;                      // C=1, ALPHA=2
    }
}

extern "C" void kernel_launch(void* const* d_in, const int* in_sizes, int n_in,
                              void* d_out, int out_size, void* d_ws, size_t ws_size,
                              hipStream_t stream) {
    const float* betas   = (const float*)d_in[0];
    const float* lambdas = (const float*)d_in[1];
    const float* gammas  = (const float*)d_in[2];
    calc_kernel<<<1, NT, 0, stream>>>(betas, lambdas, gammas, (float*)d_out);
}